// Round 1
// baseline (187.711 us; speedup 1.0000x reference)
//
#include <hip/hip_runtime.h>
#include <stdint.h>

#define SEQ 256
#define BATCH 32
#define IN_DIM 1024
#define HID 64
#define NPAD 1280
#define ROWS (SEQ*BATCH)   // 8192

// workspace layout (high-water 61,477,888 B — proven footprint):
//  [0,16.78M)      Xbf (prep->gemm), then DMh bf16 ΔM/Mstart [18.87 MB, spills into
//  [16.78M,19.40M) Wbf               dead Wbf region; ends 18,874,368 < bb @19,398,656]
//  [19.40M,..)     bb, gate (live throughout)
//  [19.53M,61.48M) Y (gemm -> mfma_chunk/corr; stays live, no overlay)
#define XBF_OFF   0
#define DMH_OFF   0
#define WBF_OFF   16777216
#define BB_OFF    19398656
#define GATE_OFF  19403776
#define Y_OFF     19534848

#define NC 8
#define CHL 32      // chunk length; 96 triples per (b,c)

// DMh: per (c,b): bf16 [m(9)][i(64)][j(64)] = 36864 u16 = 73.7 KB; total 8*32 = 18.87 MB
#define DM_CB_U32 18432

typedef __attribute__((ext_vector_type(8))) short short8;
typedef __attribute__((ext_vector_type(4))) float floatx4;

typedef const __attribute__((address_space(1))) unsigned int gas_u32;
typedef __attribute__((address_space(3))) unsigned int las_u32;
static __device__ __forceinline__ void gl_lds16(const void* g, void* l) {
  __builtin_amdgcn_global_load_lds((gas_u32*)g, (las_u32*)l, 16, 0, 0);
}

static __device__ __forceinline__ short f2bf(float f) {
  union { float f; uint32_t u; } a; a.f = f;
  uint32_t r = (a.u + 0x7FFFu + ((a.u >> 16) & 1u)) >> 16;  // RNE
  return (short)r;
}
static __device__ __forceinline__ float bflo(uint32_t u){ return __uint_as_float(u << 16); }
static __device__ __forceinline__ float bfhi(uint32_t u){ return __uint_as_float(u & 0xffff0000u); }
static __device__ __forceinline__ float bfu(unsigned short us){ return __uint_as_float(((uint32_t)us) << 16); }

// ---------------- fused prep + gate ----------------
__global__ __launch_bounds__(256) void prep_gate_kernel(
    const float* __restrict__ X,
    const float* __restrict__ Wk, const float* __restrict__ bk,
    const float* __restrict__ Wv, const float* __restrict__ bv,
    const float* __restrict__ Wg, const float* __restrict__ bg,
    const float* __restrict__ Wq, const float* __restrict__ bq,
    short* __restrict__ Xbf, short* __restrict__ Wbf,
    float* __restrict__ bb, float4* __restrict__ gate)
{
  if (blockIdx.x < 2048) {
    int64_t idx = (int64_t)blockIdx.x * blockDim.x + threadIdx.x;
    int64_t stride = (int64_t)2048 * 256;
    const int64_t NX4 = (int64_t)ROWS * IN_DIM / 4;
    for (int64_t i = idx; i < NX4; i += stride) {
      float4 x = ((const float4*)X)[i];
      short4 s4;
      s4.x = f2bf(x.x); s4.y = f2bf(x.y); s4.z = f2bf(x.z); s4.w = f2bf(x.w);
      ((short4*)Xbf)[i] = s4;
    }
    const int64_t NW4 = (int64_t)NPAD * IN_DIM / 4;
    for (int64_t i = idx; i < NW4; i += stride) {
      int64_t e = i * 4;
      int r = (int)(e >> 10);
      int k = (int)(e & 1023);
      float4 x;
      if (r < 576)       x = *(const float4*)(Wk + (int64_t)r*1024 + k);
      else if (r < 1152) x = *(const float4*)(Wv + (int64_t)(r-576)*1024 + k);
      else if (r < 1216) x = *(const float4*)(Wq + (int64_t)(r-1152)*1024 + k);
      else               x = make_float4(0.f, 0.f, 0.f, 0.f);
      short4 s4;
      s4.x = f2bf(x.x); s4.y = f2bf(x.y); s4.z = f2bf(x.z); s4.w = f2bf(x.w);
      ((short4*)Wbf)[i] = s4;
    }
    for (int64_t i = idx; i < NPAD; i += stride) {
      int r = (int)i; float v;
      if (r < 576)       v = bk[r];
      else if (r < 1152) v = bv[r - 576];
      else if (r < 1216) v = bq[r - 1152];
      else               v = 0.f;
      bb[r] = v;
    }
  } else {
    const int lane = threadIdx.x & 63;
    const int row  = (blockIdx.x - 2048) * 4 + (threadIdx.x >> 6);
    const float* x = X + (int64_t)row * IN_DIM;

    float acc[8];
#pragma unroll
    for (int e = 0; e < 8; e++) acc[e] = 0.f;
#pragma unroll
    for (int i = 0; i < 4; i++) {
      const int off = i * 256 + lane * 4;
      float4 xv = *(const float4*)(x + off);
#pragma unroll
      for (int e = 0; e < 8; e++) {
        float4 wv = *(const float4*)(Wg + e * IN_DIM + off);
        acc[e] += xv.x * wv.x + xv.y * wv.y + xv.z * wv.z + xv.w * wv.w;
      }
    }
#pragma unroll
    for (int e = 0; e < 8; e++) {
#pragma unroll
      for (int m = 32; m >= 1; m >>= 1)
        acc[e] += __shfl_xor(acc[e], m);
      acc[e] += bg[e];
    }
    if (lane == 0) {
      int i0 = 0; float v0 = acc[0];
#pragma unroll
      for (int e = 1; e < 8; e++) if (acc[e] > v0) { v0 = acc[e]; i0 = e; }
      int i1 = -1; float v1 = -3.4e38f;
#pragma unroll
      for (int e = 0; e < 8; e++) if (e != i0 && acc[e] > v1) { v1 = acc[e]; i1 = e; }
      float e1 = __expf(v1 - v0);
      float inv = 1.f / (1.f + e1);
      gate[row] = make_float4(__int_as_float(i0), __int_as_float(i1), inv, e1 * inv);
    }
  }
}

// ---------------- GEMM: double-buffered prefetch + XCD-colocating swizzle ----------------
// T3-minimum 2-phase: issue next tile's global_load_lds BEFORE ds_read+MFMA of
// current tile; single __syncthreads (vmcnt drain) per K-step. 1-D grid of 640,
// id2=(h&7)*80+(h>>3): 8 consecutive row-panels per XCD -> A panel + whole B
// (2.6MB) L2-resident per XCD.
__global__ __launch_bounds__(256) void gemm_kernel(
    const short* __restrict__ Xbf,
    const short* __restrict__ Wbf,
    const float* __restrict__ bb,
    float* __restrict__ Y)
{
  __shared__ short As[2][128 * 32];
  __shared__ short Bs[2][128 * 32];

  const int tid  = threadIdx.x;
  const int lane = tid & 63;
  const int wv   = tid >> 6;
  const int quad = lane >> 4;
  const int cl   = lane & 15;
  const int wm   = wv & 1;
  const int wn   = wv >> 1;

  // bijective XCD-colocate swizzle (640 = 8 * 80)
  const int h   = blockIdx.x;
  const int id2 = (h & 7) * 80 + (h >> 3);
  const int by  = id2 / 10;
  const int bx  = id2 - by * 10;
  const int m0  = by * 128;
  const int n0  = bx * 128;

  const int srow = wv * 32 + (lane >> 2);
  const int scol = (lane & 3) * 8;
  const short* gA = Xbf + (int64_t)(m0 + srow) * IN_DIM + scol;
  const short* gB = Wbf + (int64_t)(n0 + srow) * IN_DIM + scol;
  short* lA0 = As[0] + (wv * 32) * 32;
  short* lA1 = As[1] + (wv * 32) * 32;
  short* lB0 = Bs[0] + (wv * 32) * 32;
  short* lB1 = Bs[1] + (wv * 32) * 32;

  floatx4 acc[4][4];
#pragma unroll
  for (int i = 0; i < 4; i++)
#pragma unroll
    for (int k = 0; k < 4; k++) acc[i][k] = (floatx4){0.f, 0.f, 0.f, 0.f};

#define STAGE(LA, LB, KS) do {                          \
    gl_lds16(gA + (KS),               (LA));            \
    gl_lds16(gA + 16 * IN_DIM + (KS), (LA) + 16 * 32);  \
    gl_lds16(gB + (KS),               (LB));            \
    gl_lds16(gB + 16 * IN_DIM + (KS), (LB) + 16 * 32);  \
  } while (0)

#define COMPUTE(B) do {                                                         \
    short8 bfrag[4], afrag[4];                                                  \
    _Pragma("unroll")                                                           \
    for (int nt = 0; nt < 4; nt++)                                              \
      bfrag[nt] = *(const short8*)(&Bs[B][(wn * 64 + nt * 16 + cl) * 32 + quad * 8]); \
    _Pragma("unroll")                                                           \
    for (int mt = 0; mt < 4; mt++)                                              \
      afrag[mt] = *(const short8*)(&As[B][(wm * 64 + mt * 16 + cl) * 32 + quad * 8]); \
    _Pragma("unroll")                                                           \
    for (int mt = 0; mt < 4; mt++)                                              \
      _Pragma("unroll")                                                         \
      for (int nt = 0; nt < 4; nt++)                                            \
        acc[mt][nt] = __builtin_amdgcn_mfma_f32_16x16x32_bf16(afrag[mt], bfrag[nt], acc[mt][nt], 0, 0, 0); \
  } while (0)

  STAGE(lA0, lB0, 0);
  __syncthreads();

  for (int ks = 0; ks < IN_DIM; ks += 64) {
    // prefetch tile ks+32 into buf1 while computing buf0
    STAGE(lA1, lB1, ks + 32);
    COMPUTE(0);
    __syncthreads();                 // drains vmcnt -> buf1 ready; buf0 free
    if (ks + 64 < IN_DIM)
      STAGE(lA0, lB0, ks + 64);     // prefetch into buf0 while computing buf1
    COMPUTE(1);
    __syncthreads();
  }
#undef STAGE
#undef COMPUTE

#pragma unroll
  for (int nt = 0; nt < 4; nt++) {
    const int col = n0 + wn * 64 + nt * 16 + cl;
    const float bias = bb[col];
#pragma unroll
    for (int mt = 0; mt < 4; mt++) {
#pragma unroll
      for (int r = 0; r < 4; r++) {
        int row = m0 + wm * 64 + mt * 16 + quad * 4 + r;
        Y[(int64_t)row * NPAD + col] = acc[mt][nt][r] + bias;
      }
    }
  }
}

// ======================= MFMA chunk kernel (512 threads, 8 waves) =======================
// Per (b,c): 96 triples e=3s+u with head/slot u in {0,i0(s),i1(s)}.
//  S = Q K^T (32x96), P = W .* S with W(t,e)=[s(e)<=t]*rw(t,slot(e)),
//  o_local = P V (32x64), dM[m] = K^T diag(slot==m) V (9x 64x64).
// Frag layouts identical to gemm_kernel (A/B: [row][k], row=lane&15, k=quad*8+j;
// C: row=quad*4+reg, col=lane&15). P goes C-layout -> LDS -> A-layout.
// 512 threads: 2 waves/SIMD for latency hiding on the gathered Y loads.
__global__ __launch_bounds__(512) void mfma_chunk_kernel(
    const float* __restrict__ Y, const float4* __restrict__ gate,
    unsigned short* __restrict__ DMu, float* __restrict__ out)
{
  __shared__ uint32_t Qs[32 * 32];          // bf16 pairs [t][dpair]
  __shared__ uint32_t Ks[96 * 32];          // bf16 pairs [e][dpair]
  __shared__ unsigned short Kts[64 * 104];  // K^T [d][e], pad 96->104
  __shared__ unsigned short Vts[64 * 104];  // V^T [d][e]
  __shared__ unsigned short Ps[32 * 104];   // P   [t][e]
  __shared__ float4 gl[32];
  __shared__ uint32_t su[96];               // slot of triple e

  const int blk = blockIdx.x;
  const int c   = blk & 7;
  const int b   = blk >> 3;
  const int tid = threadIdx.x;
  const int lane = tid & 63;
  const int wv  = tid >> 6;                 // 0..7
  const int quad = lane >> 4;
  const int cl  = lane & 15;
  const int t0  = c * CHL;

  // ---- stage gates + slot ids ----
  if (tid < 32) {
    float4 g = gate[(t0 + tid) * BATCH + b];
    gl[tid] = g;
    su[3 * tid]     = 0u;
    su[3 * tid + 1] = (uint32_t)__float_as_int(g.x);
    su[3 * tid + 2] = (uint32_t)__float_as_int(g.y);
  }
  __syncthreads();

  // ---- stage K (natural + transposed), V (transposed), Q — gathered from Y via gates ----
  for (int idx = tid; idx < 3072; idx += 512) {      // e = idx>>5, dpair = idx&31
    const int e = idx >> 5, dd = idx & 31;
    const int s = (e * 171) >> 9;                    // e/3 (exact for e<96)
    const int u = e - 3 * s;
    const int head = (u == 0) ? 0 : (int)su[3 * s + u];
    const float* Yr = Y + ((int64_t)(t0 + s) * BATCH + b) * NPAD;
    float f0 = Yr[head * 64 + 2 * dd], f1 = Yr[head * 64 + 2 * dd + 1];
    unsigned short b0 = (unsigned short)f2bf(f0), b1 = (unsigned short)f2bf(f1);
    Ks[e * 32 + dd] = (uint32_t)b0 | ((uint32_t)b1 << 16);
    Kts[(2 * dd) * 104 + e] = b0;
    Kts[(2 * dd + 1) * 104 + e] = b1;
    float v0 = Yr[576 + head * 64 + 2 * dd], v1 = Yr[576 + head * 64 + 2 * dd + 1];
    Vts[(2 * dd) * 104 + e] = (unsigned short)f2bf(v0);
    Vts[(2 * dd + 1) * 104 + e] = (unsigned short)f2bf(v1);
  }
  for (int idx = tid; idx < 1024; idx += 512) {      // t = idx>>5, dpair = idx&31
    const int s = idx >> 5, dd = idx & 31;
    const float* Yr = Y + ((int64_t)(t0 + s) * BATCH + b) * NPAD;
    Qs[s * 32 + dd] = ((uint32_t)(unsigned short)f2bf(Yr[1152 + 2 * dd])) |
                      (((uint32_t)(unsigned short)f2bf(Yr[1152 + 2 * dd + 1])) << 16);
  }
  __syncthreads();

  const unsigned short* Qu = (const unsigned short*)Qs;
  const unsigned short* Ku = (const unsigned short*)Ks;

  // ---- phase S + weight + pack P : 12 C-tiles over 8 waves ----
  for (int tileId = wv; tileId < 12; tileId += 8) {
    const int mt = tileId / 6, nt = tileId % 6;
    floatx4 acc = (floatx4){0.f, 0.f, 0.f, 0.f};
#pragma unroll
    for (int kc = 0; kc < 2; kc++) {
      short8 af = *(const short8*)(Qu + (mt * 16 + cl) * 64 + kc * 32 + quad * 8);
      short8 bf = *(const short8*)(Ku + (nt * 16 + cl) * 64 + kc * 32 + quad * 8);
      acc = __builtin_amdgcn_mfma_f32_16x16x32_bf16(af, bf, acc, 0, 0, 0);
    }
    const int e = nt * 16 + cl;
    const int s_e = (e * 171) >> 9;
    const int slot_e = (int)su[e];
#pragma unroll
    for (int r = 0; r < 4; r++) {
      const int t = mt * 16 + quad * 4 + r;
      float4 g = gl[t];
      const int i0t = __float_as_int(g.x), i1t = __float_as_int(g.y);
      float w = (slot_e == 0 ? 1.f : 0.f)
              + (slot_e == i0t ? g.z : 0.f)
              + (slot_e == i1t ? g.w : 0.f);
      w = (s_e <= t) ? w : 0.f;
      Ps[t * 104 + e] = (unsigned short)f2bf(w * acc[r]);
    }
  }
  __syncthreads();

  // ---- phase PV : o_local = P V, 8 C-tiles, one per wave ----
  {
    const int tileId = wv;                    // 0..7
    const int mt = tileId >> 2, nt = tileId & 3;
    floatx4 acc = (floatx4){0.f, 0.f, 0.f, 0.f};
#pragma unroll
    for (int kc = 0; kc < 3; kc++) {
      short8 af = *(const short8*)(Ps  + (mt * 16 + cl) * 104 + kc * 32 + quad * 8);
      short8 bf = *(const short8*)(Vts + (nt * 16 + cl) * 104 + kc * 32 + quad * 8);
      acc = __builtin_amdgcn_mfma_f32_16x16x32_bf16(af, bf, acc, 0, 0, 0);
    }
#pragma unroll
    for (int r = 0; r < 4; r++) {
      const int t = mt * 16 + quad * 4 + r, j = nt * 16 + cl;
      out[(int64_t)(t0 + t) * (BATCH * HID) + b * HID + j] = acc[r];
    }
  }

  // ---- phase dM : per slot m, D = K^T diag(slot==m) V ----
  uint32_t sreg[3][8];
#pragma unroll
  for (int kc = 0; kc < 3; kc++)
#pragma unroll
    for (int jj = 0; jj < 8; jj++)
      sreg[kc][jj] = su[kc * 32 + quad * 8 + jj];

  short8 afc[4][3];
#pragma unroll
  for (int mt = 0; mt < 4; mt++)
#pragma unroll
    for (int kc = 0; kc < 3; kc++)
      afc[mt][kc] = *(const short8*)(Kts + (mt * 16 + cl) * 104 + kc * 32 + quad * 8);

  unsigned short* dmb = DMu + ((int64_t)(c * 32 + b)) * 36864;
  union U8 { short8 s; uint32_t u[4]; };

  for (int mi = wv; mi < 9; mi += 8) {        // wave0: {0,8}; waves 1..7: one each
    uint32_t md[3][4];
#pragma unroll
    for (int kc = 0; kc < 3; kc++)
#pragma unroll
      for (int p = 0; p < 4; p++)
        md[kc][p] = ((sreg[kc][2 * p]     == (uint32_t)mi) ? 0x0000ffffu : 0u) |
                    ((sreg[kc][2 * p + 1] == (uint32_t)mi) ? 0xffff0000u : 0u);
#pragma unroll
    for (int nt = 0; nt < 4; nt++) {
      short8 bm[3];
#pragma unroll
      for (int kc = 0; kc < 3; kc++) {
        U8 vv; vv.s = *(const short8*)(Vts + (nt * 16 + cl) * 104 + kc * 32 + quad * 8);
        vv.u[0] &= md[kc][0]; vv.u[1] &= md[kc][1];
        vv.u[2] &= md[kc][2]; vv.u[3] &= md[kc][3];
        bm[kc] = vv.s;
      }
#pragma unroll
      for (int mt = 0; mt < 4; mt++) {
        floatx4 acc = (floatx4){0.f, 0.f, 0.f, 0.f};
#pragma unroll
        for (int kc = 0; kc < 3; kc++)
          acc = __builtin_amdgcn_mfma_f32_16x16x32_bf16(afc[mt][kc], bm[kc], acc, 0, 0, 0);
#pragma unroll
        for (int r = 0; r < 4; r++) {
          const int i = mt * 16 + quad * 4 + r, j = nt * 16 + cl;
          dmb[mi * 4096 + i * 64 + j] = (unsigned short)f2bf(acc[r]);
        }
      }
    }
  }
}

// ---------------- prefix: ΔM(bf16) -> Mstart(bf16) exclusive +M0; writes M_final fp32 ----------------
__global__ void prefix_kernel(const float* __restrict__ M0, uint32_t* __restrict__ DMh,
                              float* __restrict__ out, int nc)
{
  int64_t e = (int64_t)blockIdx.x * blockDim.x + threadIdx.x;   // < 32*18432 u32 units
  int b = (int)(e / DM_CB_U32);
  int r = (int)(e % DM_CB_U32);             // m*2048 + i*32 + jpair
  int m = r >> 11, rem = r & 2047, i = rem >> 5, jp = rem & 31;
  int64_t f32i = (int64_t)b * 36864 + m * 4096 + i * 64 + jp * 2;
  float run0 = M0[f32i], run1 = M0[f32i + 1];
  for (int cc = 0; cc < nc; cc++) {
    int64_t idx = ((int64_t)(cc * 32 + b)) * DM_CB_U32 + r;
    uint32_t u = DMh[idx];
    DMh[idx] = ((uint32_t)(unsigned short)f2bf(run0)) |
               (((uint32_t)(unsigned short)f2bf(run1)) << 16);
    run0 += bflo(u); run1 += bfhi(u);
  }
  *(float2*)(out + (int64_t)SEQ * BATCH * HID + f32i) = make_float2(run0, run1);
}

// ---------------- corr: o += q·(Mstart[0] + g0·Mstart[i0] + g1·Mstart[i1]) ----------------
// block = (b,c,jh). q read fp32 from Y; Mstart bf16 from DMh.
__global__ __launch_bounds__(256) void corr_kernel(
    const float* __restrict__ Y, const float4* __restrict__ gate,
    const uint32_t* __restrict__ DMh, float* __restrict__ out)
{
  __shared__ uint32_t Msb32[9 * 64 * 16];   // bf16 pairs [m][i][jpair-half] = 36.9KB
  __shared__ float2 qb[32 * 32];            // q fp32 pairs [t][i/2]
  __shared__ float4 gl[32];
  unsigned short* Msb = (unsigned short*)Msb32;
  const int blk = blockIdx.x;
  const int c   = blk & 7;
  const int jh  = (blk >> 3) & 1;
  const int b   = blk >> 4;
  const int tid = threadIdx.x;
  const int t0  = c * CHL;

  if (tid < 32) gl[tid] = gate[(t0 + tid) * BATCH + b];
#pragma unroll
  for (int k = 0; k < 4; k++) {
    int f = tid + 256 * k;                // < 1024
    int t = f >> 5, p = f & 31;
    qb[t * 32 + p] = *(const float2*)(Y + ((int64_t)(t0 + t) * BATCH + b) * NPAD + 1152 + 2 * p);
  }
  const uint32_t* dmb = DMh + ((int64_t)(c * 32 + b)) * DM_CB_U32;
#pragma unroll
  for (int k = 0; k < 36; k++) {
    int f = tid + 256 * k;                // < 9216 u32
    int m = f >> 10, rem = f & 1023, i = rem >> 4, p = rem & 15;
    Msb32[(m * 64 + i) * 16 + p] = dmb[m * 2048 + i * 32 + jh * 16 + p];
  }
  __syncthreads();

  const int jj = tid & 31;
  const int tg = tid >> 5;
#pragma unroll
  for (int tt = 0; tt < 4; tt++) {
    const int t = tt * 8 + tg;
    float4 g = gl[t];
    const int i0 = __float_as_int(g.x), i1 = __float_as_int(g.y);
    const float g0 = g.z, g1 = g.w;
    float acc = 0.f;
#pragma unroll 8
    for (int i2 = 0; i2 < 32; i2++) {
      float2 qq = qb[t * 32 + i2];
      int ia = 2 * i2;
      float m0a = bfu(Msb[(0  * 64 + ia) * 32 + jj]);
      float m0b = bfu(Msb[(0  * 64 + ia + 1) * 32 + jj]);
      float maa = bfu(Msb[(i0 * 64 + ia) * 32 + jj]);
      float mab = bfu(Msb[(i0 * 64 + ia + 1) * 32 + jj]);
      float mba = bfu(Msb[(i1 * 64 + ia) * 32 + jj]);
      float mbb = bfu(Msb[(i1 * 64 + ia + 1) * 32 + jj]);
      acc += qq.x * (m0a + g0 * maa + g1 * mba);
      acc += qq.y * (m0b + g0 * mab + g1 * mbb);
    }
    float* op = out + (int64_t)(t0 + t) * (BATCH * HID) + b * HID + jh * 32 + jj;
    *op += acc;
  }
}

// ---------------- launch ----------------
extern "C" void kernel_launch(void* const* d_in, const int* in_sizes, int n_in,
                              void* d_out, int out_size, void* d_ws, size_t ws_size,
                              hipStream_t stream)
{
  const float* X  = (const float*)d_in[0];
  const float* M0 = (const float*)d_in[1];
  const float* Wk = (const float*)d_in[2];
  const float* bk = (const float*)d_in[3];
  const float* Wv = (const float*)d_in[4];
  const float* bv = (const float*)d_in[5];
  const float* Wg = (const float*)d_in[6];
  const float* bg = (const float*)d_in[7];
  const float* Wq = (const float*)d_in[8];
  const float* bq = (const float*)d_in[9];

  char* ws = (char*)d_ws;
  short*          Xbf  = (short*)(ws + XBF_OFF);
  short*          Wbf  = (short*)(ws + WBF_OFF);
  float*          bb   = (float*)(ws + BB_OFF);
  float4*         gate = (float4*)(ws + GATE_OFF);
  float*          Y    = (float*)(ws + Y_OFF);
  uint32_t*       DMh  = (uint32_t*)(ws + DMH_OFF);        // overlays Xbf/Wbf (dead after gemm)
  unsigned short* DMu  = (unsigned short*)(ws + DMH_OFF);
  float*          out  = (float*)d_out;

  prep_gate_kernel<<<4096, 256, 0, stream>>>(X, Wk, bk, Wv, bv, Wg, bg, Wq, bq,
                                             Xbf, Wbf, bb, gate);
  gemm_kernel<<<640, 256, 0, stream>>>(Xbf, Wbf, bb, Y);
  mfma_chunk_kernel<<<32 * NC, 512, 0, stream>>>(Y, gate, DMu, out);
  prefix_kernel<<<(32 * DM_CB_U32) / 256, 256, 0, stream>>>(M0, DMh, out, NC);
  corr_kernel<<<32 * NC * 2, 256, 0, stream>>>(Y, gate, DMh, out);
}

// Round 2
// 173.766 us; speedup vs baseline: 1.0803x; 1.0803x over previous
//
#include <hip/hip_runtime.h>
#include <stdint.h>

#define SEQ 256
#define BATCH 32
#define IN_DIM 1024
#define HID 64
#define NPAD 1280
#define ROWS (SEQ*BATCH)   // 8192

// workspace layout (high-water 61,477,888 B — proven footprint):
//  [0,16.78M)      Xbf (prep->gemm), then DMh bf16 ΔM/Mstart [18.87 MB, spills into
//  [16.78M,19.40M) Wbf               dead Wbf region; ends 18,874,368 < bb @19,398,656]
//  [19.40M,..)     bb, gate (live throughout)
//  [19.53M,61.48M) Y (gemm -> mfma_chunk/corr; stays live, no overlay)
#define XBF_OFF   0
#define DMH_OFF   0
#define WBF_OFF   16777216
#define BB_OFF    19398656
#define GATE_OFF  19403776
#define Y_OFF     19534848

#define NC 8
#define CHL 32      // chunk length; 96 triples per (b,c)

// DMh: per (c,b): bf16 [m(9)][i(64)][j(64)] = 36864 u16 = 73.7 KB; total 8*32 = 18.87 MB
#define DM_CB_U32 18432

typedef __attribute__((ext_vector_type(8))) short short8;
typedef __attribute__((ext_vector_type(4))) float floatx4;

typedef const __attribute__((address_space(1))) unsigned int gas_u32;
typedef __attribute__((address_space(3))) unsigned int las_u32;
static __device__ __forceinline__ void gl_lds16(const void* g, void* l) {
  __builtin_amdgcn_global_load_lds((gas_u32*)g, (las_u32*)l, 16, 0, 0);
}

static __device__ __forceinline__ short f2bf(float f) {
  union { float f; uint32_t u; } a; a.f = f;
  uint32_t r = (a.u + 0x7FFFu + ((a.u >> 16) & 1u)) >> 16;  // RNE
  return (short)r;
}
static __device__ __forceinline__ float bflo(uint32_t u){ return __uint_as_float(u << 16); }
static __device__ __forceinline__ float bfhi(uint32_t u){ return __uint_as_float(u & 0xffff0000u); }
static __device__ __forceinline__ float bfu(unsigned short us){ return __uint_as_float(((uint32_t)us) << 16); }

// ---------------- fused prep + gate ----------------
__global__ __launch_bounds__(256) void prep_gate_kernel(
    const float* __restrict__ X,
    const float* __restrict__ Wk, const float* __restrict__ bk,
    const float* __restrict__ Wv, const float* __restrict__ bv,
    const float* __restrict__ Wg, const float* __restrict__ bg,
    const float* __restrict__ Wq, const float* __restrict__ bq,
    short* __restrict__ Xbf, short* __restrict__ Wbf,
    float* __restrict__ bb, float4* __restrict__ gate)
{
  if (blockIdx.x < 2048) {
    int64_t idx = (int64_t)blockIdx.x * blockDim.x + threadIdx.x;
    int64_t stride = (int64_t)2048 * 256;
    const int64_t NX4 = (int64_t)ROWS * IN_DIM / 4;
    for (int64_t i = idx; i < NX4; i += stride) {
      float4 x = ((const float4*)X)[i];
      short4 s4;
      s4.x = f2bf(x.x); s4.y = f2bf(x.y); s4.z = f2bf(x.z); s4.w = f2bf(x.w);
      ((short4*)Xbf)[i] = s4;
    }
    const int64_t NW4 = (int64_t)NPAD * IN_DIM / 4;
    for (int64_t i = idx; i < NW4; i += stride) {
      int64_t e = i * 4;
      int r = (int)(e >> 10);
      int k = (int)(e & 1023);
      float4 x;
      if (r < 576)       x = *(const float4*)(Wk + (int64_t)r*1024 + k);
      else if (r < 1152) x = *(const float4*)(Wv + (int64_t)(r-576)*1024 + k);
      else if (r < 1216) x = *(const float4*)(Wq + (int64_t)(r-1152)*1024 + k);
      else               x = make_float4(0.f, 0.f, 0.f, 0.f);
      short4 s4;
      s4.x = f2bf(x.x); s4.y = f2bf(x.y); s4.z = f2bf(x.z); s4.w = f2bf(x.w);
      ((short4*)Wbf)[i] = s4;
    }
    for (int64_t i = idx; i < NPAD; i += stride) {
      int r = (int)i; float v;
      if (r < 576)       v = bk[r];
      else if (r < 1152) v = bv[r - 576];
      else if (r < 1216) v = bq[r - 1152];
      else               v = 0.f;
      bb[r] = v;
    }
  } else {
    const int lane = threadIdx.x & 63;
    const int row  = (blockIdx.x - 2048) * 4 + (threadIdx.x >> 6);
    const float* x = X + (int64_t)row * IN_DIM;

    float acc[8];
#pragma unroll
    for (int e = 0; e < 8; e++) acc[e] = 0.f;
#pragma unroll
    for (int i = 0; i < 4; i++) {
      const int off = i * 256 + lane * 4;
      float4 xv = *(const float4*)(x + off);
#pragma unroll
      for (int e = 0; e < 8; e++) {
        float4 wv = *(const float4*)(Wg + e * IN_DIM + off);
        acc[e] += xv.x * wv.x + xv.y * wv.y + xv.z * wv.z + xv.w * wv.w;
      }
    }
#pragma unroll
    for (int e = 0; e < 8; e++) {
#pragma unroll
      for (int m = 32; m >= 1; m >>= 1)
        acc[e] += __shfl_xor(acc[e], m);
      acc[e] += bg[e];
    }
    if (lane == 0) {
      int i0 = 0; float v0 = acc[0];
#pragma unroll
      for (int e = 1; e < 8; e++) if (acc[e] > v0) { v0 = acc[e]; i0 = e; }
      int i1 = -1; float v1 = -3.4e38f;
#pragma unroll
      for (int e = 0; e < 8; e++) if (e != i0 && acc[e] > v1) { v1 = acc[e]; i1 = e; }
      float e1 = __expf(v1 - v0);
      float inv = 1.f / (1.f + e1);
      gate[row] = make_float4(__int_as_float(i0), __int_as_float(i1), inv, e1 * inv);
    }
  }
}

// ---------------- GEMM (round-0 verified structure: 40.2 us) ----------------
__global__ __launch_bounds__(256) void gemm_kernel(
    const short* __restrict__ Xbf,
    const short* __restrict__ Wbf,
    const float* __restrict__ bb,
    float* __restrict__ Y)
{
  __shared__ short As[128 * 32];
  __shared__ short Bs[128 * 32];

  const int tid  = threadIdx.x;
  const int lane = tid & 63;
  const int wv   = tid >> 6;
  const int quad = lane >> 4;
  const int cl   = lane & 15;
  const int wm   = wv & 1;
  const int wn   = wv >> 1;
  const int m0 = blockIdx.y * 128;
  const int n0 = blockIdx.x * 128;

  const int srow = wv * 32 + (lane >> 2);
  const int scol = (lane & 3) * 8;
  const short* gA = Xbf + (int64_t)(m0 + srow) * IN_DIM + scol;
  const short* gB = Wbf + (int64_t)(n0 + srow) * IN_DIM + scol;
  short* lA = As + (wv * 32) * 32;
  short* lB = Bs + (wv * 32) * 32;

  floatx4 acc[4][4];
#pragma unroll
  for (int i = 0; i < 4; i++)
#pragma unroll
    for (int k = 0; k < 4; k++) acc[i][k] = (floatx4){0.f, 0.f, 0.f, 0.f};

  for (int ks = 0; ks < IN_DIM; ks += 32) {
    gl_lds16(gA + ks,                lA);
    gl_lds16(gA + 16 * IN_DIM + ks,  lA + 16 * 32);
    gl_lds16(gB + ks,                lB);
    gl_lds16(gB + 16 * IN_DIM + ks,  lB + 16 * 32);
    __syncthreads();

    short8 bfrag[4], afrag[4];
#pragma unroll
    for (int nt = 0; nt < 4; nt++)
      bfrag[nt] = *(const short8*)(&Bs[(wn * 64 + nt * 16 + cl) * 32 + quad * 8]);
#pragma unroll
    for (int mt = 0; mt < 4; mt++)
      afrag[mt] = *(const short8*)(&As[(wm * 64 + mt * 16 + cl) * 32 + quad * 8]);
#pragma unroll
    for (int mt = 0; mt < 4; mt++)
#pragma unroll
      for (int nt = 0; nt < 4; nt++)
        acc[mt][nt] = __builtin_amdgcn_mfma_f32_16x16x32_bf16(afrag[mt], bfrag[nt], acc[mt][nt], 0, 0, 0);
    __syncthreads();
  }

#pragma unroll
  for (int nt = 0; nt < 4; nt++) {
    const int col = n0 + wn * 64 + nt * 16 + cl;
    const float bias = bb[col];
#pragma unroll
    for (int mt = 0; mt < 4; mt++) {
#pragma unroll
      for (int r = 0; r < 4; r++) {
        int row = m0 + wm * 64 + mt * 16 + quad * 4 + r;
        Y[(int64_t)row * NPAD + col] = acc[mt][nt][r] + bias;
      }
    }
  }
}

// ======================= MFMA chunk kernel (512 threads, 8 waves) =======================
// Per (b,c): 96 triples e=3s+u with head/slot u in {0,i0(s),i1(s)}.
//  S = Q K^T (32x96), P = W .* S with W(t,e)=[s(e)<=t]*rw(t,slot(e)),
//  o_local = P V (32x64), dM[m] = K^T diag(slot==m) V (9x 64x64).
// Staging vectorized: float4 gathers from Y, uint2 LDS writes for Ks/Qs.
__global__ __launch_bounds__(512) void mfma_chunk_kernel(
    const float* __restrict__ Y, const float4* __restrict__ gate,
    unsigned short* __restrict__ DMu, float* __restrict__ out)
{
  __shared__ uint32_t Qs[32 * 32];          // bf16 pairs [t][dpair]
  __shared__ uint32_t Ks[96 * 32];          // bf16 pairs [e][dpair]
  __shared__ unsigned short Kts[64 * 104];  // K^T [d][e], pad 96->104
  __shared__ unsigned short Vts[64 * 104];  // V^T [d][e]
  __shared__ unsigned short Ps[32 * 104];   // P   [t][e]
  __shared__ float4 gl[32];
  __shared__ uint32_t su[96];               // slot of triple e

  const int blk = blockIdx.x;
  const int c   = blk & 7;
  const int b   = blk >> 3;
  const int tid = threadIdx.x;
  const int lane = tid & 63;
  const int wv  = tid >> 6;                 // 0..7
  const int quad = lane >> 4;
  const int cl  = lane & 15;
  const int t0  = c * CHL;

  // ---- stage gates + slot ids ----
  if (tid < 32) {
    float4 g = gate[(t0 + tid) * BATCH + b];
    gl[tid] = g;
    su[3 * tid]     = 0u;
    su[3 * tid + 1] = (uint32_t)__float_as_int(g.x);
    su[3 * tid + 2] = (uint32_t)__float_as_int(g.y);
  }
  __syncthreads();

  // ---- stage K (natural + transposed), V (transposed) — float4 gathers ----
  for (int idx = tid; idx < 1536; idx += 512) {      // e = idx>>4, d4 = idx&15
    const int e = idx >> 4, d4 = idx & 15;
    const int s = (e * 171) >> 9;                    // e/3 (exact for e<96)
    const int u = e - 3 * s;
    const int head = (u == 0) ? 0 : (int)su[3 * s + u];
    const float* Yr = Y + ((int64_t)(t0 + s) * BATCH + b) * NPAD;
    float4 kf = *(const float4*)(Yr + head * 64 + 4 * d4);
    unsigned short k0 = (unsigned short)f2bf(kf.x), k1 = (unsigned short)f2bf(kf.y);
    unsigned short k2 = (unsigned short)f2bf(kf.z), k3 = (unsigned short)f2bf(kf.w);
    uint2 kp; kp.x = (uint32_t)k0 | ((uint32_t)k1 << 16);
    kp.y = (uint32_t)k2 | ((uint32_t)k3 << 16);
    *(uint2*)&Ks[e * 32 + 2 * d4] = kp;
    Kts[(4 * d4)     * 104 + e] = k0;
    Kts[(4 * d4 + 1) * 104 + e] = k1;
    Kts[(4 * d4 + 2) * 104 + e] = k2;
    Kts[(4 * d4 + 3) * 104 + e] = k3;
    float4 vf = *(const float4*)(Yr + 576 + head * 64 + 4 * d4);
    Vts[(4 * d4)     * 104 + e] = (unsigned short)f2bf(vf.x);
    Vts[(4 * d4 + 1) * 104 + e] = (unsigned short)f2bf(vf.y);
    Vts[(4 * d4 + 2) * 104 + e] = (unsigned short)f2bf(vf.z);
    Vts[(4 * d4 + 3) * 104 + e] = (unsigned short)f2bf(vf.w);
  }
  {                                                   // Q: 512 entries, one per thread
    const int s = tid >> 4, d4 = tid & 15;
    const float* Yr = Y + ((int64_t)(t0 + s) * BATCH + b) * NPAD;
    float4 qf = *(const float4*)(Yr + 1152 + 4 * d4);
    uint2 qp;
    qp.x = (uint32_t)(unsigned short)f2bf(qf.x) | (((uint32_t)(unsigned short)f2bf(qf.y)) << 16);
    qp.y = (uint32_t)(unsigned short)f2bf(qf.z) | (((uint32_t)(unsigned short)f2bf(qf.w)) << 16);
    *(uint2*)&Qs[s * 32 + 2 * d4] = qp;
  }
  __syncthreads();

  const unsigned short* Qu = (const unsigned short*)Qs;
  const unsigned short* Ku = (const unsigned short*)Ks;

  // ---- phase S + weight + pack P : 12 C-tiles over 8 waves ----
  for (int tileId = wv; tileId < 12; tileId += 8) {
    const int mt = tileId / 6, nt = tileId % 6;
    floatx4 acc = (floatx4){0.f, 0.f, 0.f, 0.f};
#pragma unroll
    for (int kc = 0; kc < 2; kc++) {
      short8 af = *(const short8*)(Qu + (mt * 16 + cl) * 64 + kc * 32 + quad * 8);
      short8 bf = *(const short8*)(Ku + (nt * 16 + cl) * 64 + kc * 32 + quad * 8);
      acc = __builtin_amdgcn_mfma_f32_16x16x32_bf16(af, bf, acc, 0, 0, 0);
    }
    const int e = nt * 16 + cl;
    const int s_e = (e * 171) >> 9;
    const int slot_e = (int)su[e];
#pragma unroll
    for (int r = 0; r < 4; r++) {
      const int t = mt * 16 + quad * 4 + r;
      float4 g = gl[t];
      const int i0t = __float_as_int(g.x), i1t = __float_as_int(g.y);
      float w = (slot_e == 0 ? 1.f : 0.f)
              + (slot_e == i0t ? g.z : 0.f)
              + (slot_e == i1t ? g.w : 0.f);
      w = (s_e <= t) ? w : 0.f;
      Ps[t * 104 + e] = (unsigned short)f2bf(w * acc[r]);
    }
  }
  __syncthreads();

  // ---- phase PV : o_local = P V, 8 C-tiles, one per wave ----
  {
    const int tileId = wv;                    // 0..7
    const int mt = tileId >> 2, nt = tileId & 3;
    floatx4 acc = (floatx4){0.f, 0.f, 0.f, 0.f};
#pragma unroll
    for (int kc = 0; kc < 3; kc++) {
      short8 af = *(const short8*)(Ps  + (mt * 16 + cl) * 104 + kc * 32 + quad * 8);
      short8 bf = *(const short8*)(Vts + (nt * 16 + cl) * 104 + kc * 32 + quad * 8);
      acc = __builtin_amdgcn_mfma_f32_16x16x32_bf16(af, bf, acc, 0, 0, 0);
    }
#pragma unroll
    for (int r = 0; r < 4; r++) {
      const int t = mt * 16 + quad * 4 + r, j = nt * 16 + cl;
      out[(int64_t)(t0 + t) * (BATCH * HID) + b * HID + j] = acc[r];
    }
  }

  // ---- phase dM : per slot m, D = K^T diag(slot==m) V ----
  uint32_t sreg[3][8];
#pragma unroll
  for (int kc = 0; kc < 3; kc++)
#pragma unroll
    for (int jj = 0; jj < 8; jj++)
      sreg[kc][jj] = su[kc * 32 + quad * 8 + jj];

  short8 afc[4][3];
#pragma unroll
  for (int mt = 0; mt < 4; mt++)
#pragma unroll
    for (int kc = 0; kc < 3; kc++)
      afc[mt][kc] = *(const short8*)(Kts + (mt * 16 + cl) * 104 + kc * 32 + quad * 8);

  unsigned short* dmb = DMu + ((int64_t)(c * 32 + b)) * 36864;
  union U8 { short8 s; uint32_t u[4]; };

  for (int mi = wv; mi < 9; mi += 8) {        // wave0: {0,8}; waves 1..7: one each
    uint32_t md[3][4];
#pragma unroll
    for (int kc = 0; kc < 3; kc++)
#pragma unroll
      for (int p = 0; p < 4; p++)
        md[kc][p] = ((sreg[kc][2 * p]     == (uint32_t)mi) ? 0x0000ffffu : 0u) |
                    ((sreg[kc][2 * p + 1] == (uint32_t)mi) ? 0xffff0000u : 0u);
#pragma unroll
    for (int nt = 0; nt < 4; nt++) {
      short8 bm[3];
#pragma unroll
      for (int kc = 0; kc < 3; kc++) {
        U8 vv; vv.s = *(const short8*)(Vts + (nt * 16 + cl) * 104 + kc * 32 + quad * 8);
        vv.u[0] &= md[kc][0]; vv.u[1] &= md[kc][1];
        vv.u[2] &= md[kc][2]; vv.u[3] &= md[kc][3];
        bm[kc] = vv.s;
      }
#pragma unroll
      for (int mt = 0; mt < 4; mt++) {
        floatx4 acc = (floatx4){0.f, 0.f, 0.f, 0.f};
#pragma unroll
        for (int kc = 0; kc < 3; kc++)
          acc = __builtin_amdgcn_mfma_f32_16x16x32_bf16(afc[mt][kc], bm[kc], acc, 0, 0, 0);
#pragma unroll
        for (int r = 0; r < 4; r++) {
          const int i = mt * 16 + quad * 4 + r, j = nt * 16 + cl;
          dmb[mi * 4096 + i * 64 + j] = (unsigned short)f2bf(acc[r]);
        }
      }
    }
  }
}

// ---------------- prefix: ΔM(bf16) -> Mstart(bf16) exclusive +M0; writes M_final fp32 ----------------
// NC hardcoded -> all 8 loads issue up front (1 latency instead of 8 dependent round trips).
__global__ void prefix_kernel(const float* __restrict__ M0, uint32_t* __restrict__ DMh,
                              float* __restrict__ out)
{
  int64_t e = (int64_t)blockIdx.x * blockDim.x + threadIdx.x;   // < 32*18432 u32 units
  int b = (int)(e / DM_CB_U32);
  int r = (int)(e % DM_CB_U32);             // m*2048 + i*32 + jpair
  int m = r >> 11, rem = r & 2047, i = rem >> 5, jp = rem & 31;
  int64_t f32i = (int64_t)b * 36864 + m * 4096 + i * 64 + jp * 2;
  float run0 = M0[f32i], run1 = M0[f32i + 1];
  uint32_t u[NC];
#pragma unroll
  for (int cc = 0; cc < NC; cc++)
    u[cc] = DMh[((int64_t)(cc * 32 + b)) * DM_CB_U32 + r];
#pragma unroll
  for (int cc = 0; cc < NC; cc++) {
    int64_t idx = ((int64_t)(cc * 32 + b)) * DM_CB_U32 + r;
    DMh[idx] = ((uint32_t)(unsigned short)f2bf(run0)) |
               (((uint32_t)(unsigned short)f2bf(run1)) << 16);
    run0 += bflo(u[cc]); run1 += bfhi(u[cc]);
  }
  *(float2*)(out + (int64_t)SEQ * BATCH * HID + f32i) = make_float2(run0, run1);
}

// ---------------- corr: o += q·(Mstart[0] + g0·Mstart[i0] + g1·Mstart[i1]) ----------------
// block = (b,c,jh). Mstart staged TRANSPOSED [m][j_local][i] (row stride 68 u16,
// bank stride 34 == 2 mod 32 -> conflict-free b64 reads). Inner loop reads 3x b64
// per 4 i's instead of 6 scalar u16 per 2 i's: ~4x fewer LDS instructions.
__global__ __launch_bounds__(256) void corr_kernel(
    const float* __restrict__ Y, const float4* __restrict__ gate,
    const uint32_t* __restrict__ DMh, float* __restrict__ out)
{
  __shared__ unsigned short MsbT[9 * 32 * 68];   // 39,168 B
  __shared__ float2 qb[32 * 32];                 // q fp32 pairs [t][i/2]
  __shared__ float4 gl[32];
  const int blk = blockIdx.x;
  const int c   = blk & 7;
  const int jh  = (blk >> 3) & 1;
  const int b   = blk >> 4;
  const int tid = threadIdx.x;
  const int t0  = c * CHL;

  if (tid < 32) gl[tid] = gate[(t0 + tid) * BATCH + b];
#pragma unroll
  for (int k = 0; k < 4; k++) {
    int f = tid + 256 * k;                // < 1024
    int t = f >> 5, p = f & 31;
    qb[t * 32 + p] = *(const float2*)(Y + ((int64_t)(t0 + t) * BATCH + b) * NPAD + 1152 + 2 * p);
  }
  const uint32_t* dmb = DMh + ((int64_t)(c * 32 + b)) * DM_CB_U32;
#pragma unroll
  for (int k = 0; k < 36; k++) {
    int f = tid + 256 * k;                // < 9216 u32
    int m = f >> 10, rem = f & 1023, i = rem >> 4, p = rem & 15;
    uint32_t u = dmb[m * 2048 + i * 32 + jh * 16 + p];
    MsbT[(m * 32 + 2 * p)     * 68 + i] = (unsigned short)(u & 0xffffu);
    MsbT[(m * 32 + 2 * p + 1) * 68 + i] = (unsigned short)(u >> 16);
  }
  __syncthreads();

  const int jj = tid & 31;
  const int tg = tid >> 5;
#pragma unroll
  for (int tt = 0; tt < 4; tt++) {
    const int t = tt * 8 + tg;
    float4 g = gl[t];
    const int i0 = __float_as_int(g.x), i1 = __float_as_int(g.y);
    const float g0 = g.z, g1 = g.w;
    const unsigned short* P0 = MsbT + (0  * 32 + jj) * 68;
    const unsigned short* Pa = MsbT + (i0 * 32 + jj) * 68;
    const unsigned short* Pb = MsbT + (i1 * 32 + jj) * 68;
    float acc = 0.f;
#pragma unroll 4
    for (int i4 = 0; i4 < 16; i4++) {     // 4 i's per step
      float2 qq0 = qb[t * 32 + 2 * i4];
      float2 qq1 = qb[t * 32 + 2 * i4 + 1];
      uint2 a0 = *(const uint2*)(P0 + 4 * i4);
      uint2 aa = *(const uint2*)(Pa + 4 * i4);
      uint2 ab = *(const uint2*)(Pb + 4 * i4);
      acc += qq0.x * (bflo(a0.x) + g0 * bflo(aa.x) + g1 * bflo(ab.x));
      acc += qq0.y * (bfhi(a0.x) + g0 * bfhi(aa.x) + g1 * bfhi(ab.x));
      acc += qq1.x * (bflo(a0.y) + g0 * bflo(aa.y) + g1 * bflo(ab.y));
      acc += qq1.y * (bfhi(a0.y) + g0 * bfhi(aa.y) + g1 * bfhi(ab.y));
    }
    float* op = out + (int64_t)(t0 + t) * (BATCH * HID) + b * HID + jh * 32 + jj;
    *op += acc;
  }
}

// ---------------- launch ----------------
extern "C" void kernel_launch(void* const* d_in, const int* in_sizes, int n_in,
                              void* d_out, int out_size, void* d_ws, size_t ws_size,
                              hipStream_t stream)
{
  const float* X  = (const float*)d_in[0];
  const float* M0 = (const float*)d_in[1];
  const float* Wk = (const float*)d_in[2];
  const float* bk = (const float*)d_in[3];
  const float* Wv = (const float*)d_in[4];
  const float* bv = (const float*)d_in[5];
  const float* Wg = (const float*)d_in[6];
  const float* bg = (const float*)d_in[7];
  const float* Wq = (const float*)d_in[8];
  const float* bq = (const float*)d_in[9];

  char* ws = (char*)d_ws;
  short*          Xbf  = (short*)(ws + XBF_OFF);
  short*          Wbf  = (short*)(ws + WBF_OFF);
  float*          bb   = (float*)(ws + BB_OFF);
  float4*         gate = (float4*)(ws + GATE_OFF);
  float*          Y    = (float*)(ws + Y_OFF);
  uint32_t*       DMh  = (uint32_t*)(ws + DMH_OFF);        // overlays Xbf/Wbf (dead after gemm)
  unsigned short* DMu  = (unsigned short*)(ws + DMH_OFF);
  float*          out  = (float*)d_out;

  prep_gate_kernel<<<4096, 256, 0, stream>>>(X, Wk, bk, Wv, bv, Wg, bg, Wq, bq,
                                             Xbf, Wbf, bb, gate);
  dim3 gg(NPAD / 128, ROWS / 128);
  gemm_kernel<<<gg, 256, 0, stream>>>(Xbf, Wbf, bb, Y);
  mfma_chunk_kernel<<<32 * NC, 512, 0, stream>>>(Y, gate, DMu, out);
  prefix_kernel<<<(32 * DM_CB_U32) / 256, 256, 0, stream>>>(M0, DMh, out);
  corr_kernel<<<32 * NC * 2, 256, 0, stream>>>(Y, gate, DMh, out);
}

// Round 3
// 168.178 us; speedup vs baseline: 1.1161x; 1.0332x over previous
//
#include <hip/hip_runtime.h>
#include <stdint.h>

#define SEQ 256
#define BATCH 32
#define IN_DIM 1024
#define HID 64
#define NPAD 1280
#define ROWS (SEQ*BATCH)   // 8192

// workspace layout (high-water 61,477,888 B — proven footprint):
//  [0,16.78M)      Xbf (prep->gemm), then DMh bf16 ΔM/Mstart [18.87 MB, spills into
//  [16.78M,19.40M) Wbf               dead Wbf region; ends 18,874,368 < bb @19,398,656]
//  [19.40M,..)     bb, gate (live throughout)
//  [19.53M,61.48M) Y (gemm -> mfma_chunk/corr; stays live, no overlay)
#define XBF_OFF   0
#define DMH_OFF   0
#define WBF_OFF   16777216
#define BB_OFF    19398656
#define GATE_OFF  19403776
#define Y_OFF     19534848

#define NC 8
#define CHL 32      // chunk length; 96 triples per (b,c)

// DMh: per (c,b): bf16 [m(9)][i(64)][j(64)] = 36864 u16 = 73.7 KB; total 8*32 = 18.87 MB
#define DM_CB_U32 18432

typedef __attribute__((ext_vector_type(8))) short short8;
typedef __attribute__((ext_vector_type(4))) float floatx4;

typedef const __attribute__((address_space(1))) unsigned int gas_u32;
typedef __attribute__((address_space(3))) unsigned int las_u32;
static __device__ __forceinline__ void gl_lds16(const void* g, void* l) {
  __builtin_amdgcn_global_load_lds((gas_u32*)g, (las_u32*)l, 16, 0, 0);
}

static __device__ __forceinline__ short f2bf(float f) {
  union { float f; uint32_t u; } a; a.f = f;
  uint32_t r = (a.u + 0x7FFFu + ((a.u >> 16) & 1u)) >> 16;  // RNE
  return (short)r;
}
static __device__ __forceinline__ float bflo(uint32_t u){ return __uint_as_float(u << 16); }
static __device__ __forceinline__ float bfhi(uint32_t u){ return __uint_as_float(u & 0xffff0000u); }
static __device__ __forceinline__ float bfu(unsigned short us){ return __uint_as_float(((uint32_t)us) << 16); }

// ---------------- fused prep + gate ----------------
// Blocks [0,2048): row-wise — cast X->bf16 AND compute gate in ONE pass (X read once).
// Blocks [2048,2304): W cast + bias pack.
__global__ __launch_bounds__(256) void prep_gate_kernel(
    const float* __restrict__ X,
    const float* __restrict__ Wk, const float* __restrict__ bk,
    const float* __restrict__ Wv, const float* __restrict__ bv,
    const float* __restrict__ Wg, const float* __restrict__ bg,
    const float* __restrict__ Wq, const float* __restrict__ bq,
    short* __restrict__ Xbf, short* __restrict__ Wbf,
    float* __restrict__ bb, float4* __restrict__ gate)
{
  if (blockIdx.x < 2048) {
    const int lane = threadIdx.x & 63;
    const int row  = blockIdx.x * 4 + (threadIdx.x >> 6);
    const float* x = X + (int64_t)row * IN_DIM;
    short4* xb = (short4*)(Xbf + (int64_t)row * IN_DIM);

    float acc[8];
#pragma unroll
    for (int e = 0; e < 8; e++) acc[e] = 0.f;
#pragma unroll
    for (int i = 0; i < 4; i++) {
      const int off = i * 256 + lane * 4;
      float4 xv = *(const float4*)(x + off);
      short4 s4;
      s4.x = f2bf(xv.x); s4.y = f2bf(xv.y); s4.z = f2bf(xv.z); s4.w = f2bf(xv.w);
      xb[i * 64 + lane] = s4;
#pragma unroll
      for (int e = 0; e < 8; e++) {
        float4 wv = *(const float4*)(Wg + e * IN_DIM + off);
        acc[e] += xv.x * wv.x + xv.y * wv.y + xv.z * wv.z + xv.w * wv.w;
      }
    }
#pragma unroll
    for (int e = 0; e < 8; e++) {
#pragma unroll
      for (int m = 32; m >= 1; m >>= 1)
        acc[e] += __shfl_xor(acc[e], m);
      acc[e] += bg[e];
    }
    if (lane == 0) {
      int i0 = 0; float v0 = acc[0];
#pragma unroll
      for (int e = 1; e < 8; e++) if (acc[e] > v0) { v0 = acc[e]; i0 = e; }
      int i1 = -1; float v1 = -3.4e38f;
#pragma unroll
      for (int e = 0; e < 8; e++) if (e != i0 && acc[e] > v1) { v1 = acc[e]; i1 = e; }
      float e1 = __expf(v1 - v0);
      float inv = 1.f / (1.f + e1);
      gate[row] = make_float4(__int_as_float(i0), __int_as_float(i1), inv, e1 * inv);
    }
  } else {
    const int idx = (blockIdx.x - 2048) * 256 + threadIdx.x;   // 65536 threads
    const int NW4 = NPAD * IN_DIM / 4;                         // 327680
#pragma unroll
    for (int i = idx; i < NW4; i += 65536) {
      int e = i * 4;
      int r = e >> 10;
      int k = e & 1023;
      float4 x;
      if (r < 576)       x = *(const float4*)(Wk + (int64_t)r*1024 + k);
      else if (r < 1152) x = *(const float4*)(Wv + (int64_t)(r-576)*1024 + k);
      else if (r < 1216) x = *(const float4*)(Wq + (int64_t)(r-1152)*1024 + k);
      else               x = make_float4(0.f, 0.f, 0.f, 0.f);
      short4 s4;
      s4.x = f2bf(x.x); s4.y = f2bf(x.y); s4.z = f2bf(x.z); s4.w = f2bf(x.w);
      ((short4*)Wbf)[i] = s4;
    }
    if (idx < NPAD) {
      int r = idx; float v;
      if (r < 576)       v = bk[r];
      else if (r < 1152) v = bv[r - 576];
      else if (r < 1216) v = bq[r - 1152];
      else               v = 0.f;
      bb[r] = v;
    }
  }
}

// ---------------- GEMM (round-0 verified structure: 40.2 us) ----------------
__global__ __launch_bounds__(256) void gemm_kernel(
    const short* __restrict__ Xbf,
    const short* __restrict__ Wbf,
    const float* __restrict__ bb,
    float* __restrict__ Y)
{
  __shared__ short As[128 * 32];
  __shared__ short Bs[128 * 32];

  const int tid  = threadIdx.x;
  const int lane = tid & 63;
  const int wv   = tid >> 6;
  const int quad = lane >> 4;
  const int cl   = lane & 15;
  const int wm   = wv & 1;
  const int wn   = wv >> 1;
  const int m0 = blockIdx.y * 128;
  const int n0 = blockIdx.x * 128;

  const int srow = wv * 32 + (lane >> 2);
  const int scol = (lane & 3) * 8;
  const short* gA = Xbf + (int64_t)(m0 + srow) * IN_DIM + scol;
  const short* gB = Wbf + (int64_t)(n0 + srow) * IN_DIM + scol;
  short* lA = As + (wv * 32) * 32;
  short* lB = Bs + (wv * 32) * 32;

  floatx4 acc[4][4];
#pragma unroll
  for (int i = 0; i < 4; i++)
#pragma unroll
    for (int k = 0; k < 4; k++) acc[i][k] = (floatx4){0.f, 0.f, 0.f, 0.f};

  for (int ks = 0; ks < IN_DIM; ks += 32) {
    gl_lds16(gA + ks,                lA);
    gl_lds16(gA + 16 * IN_DIM + ks,  lA + 16 * 32);
    gl_lds16(gB + ks,                lB);
    gl_lds16(gB + 16 * IN_DIM + ks,  lB + 16 * 32);
    __syncthreads();

    short8 bfrag[4], afrag[4];
#pragma unroll
    for (int nt = 0; nt < 4; nt++)
      bfrag[nt] = *(const short8*)(&Bs[(wn * 64 + nt * 16 + cl) * 32 + quad * 8]);
#pragma unroll
    for (int mt = 0; mt < 4; mt++)
      afrag[mt] = *(const short8*)(&As[(wm * 64 + mt * 16 + cl) * 32 + quad * 8]);
#pragma unroll
    for (int mt = 0; mt < 4; mt++)
#pragma unroll
      for (int nt = 0; nt < 4; nt++)
        acc[mt][nt] = __builtin_amdgcn_mfma_f32_16x16x32_bf16(afrag[mt], bfrag[nt], acc[mt][nt], 0, 0, 0);
    __syncthreads();
  }

#pragma unroll
  for (int nt = 0; nt < 4; nt++) {
    const int col = n0 + wn * 64 + nt * 16 + cl;
    const float bias = bb[col];
#pragma unroll
    for (int mt = 0; mt < 4; mt++) {
#pragma unroll
      for (int r = 0; r < 4; r++) {
        int row = m0 + wm * 64 + mt * 16 + quad * 4 + r;
        Y[(int64_t)row * NPAD + col] = acc[mt][nt][r] + bias;
      }
    }
  }
}

// ======================= MFMA chunk kernel (512 threads, 8 waves) =======================
// Per (b,c): 96 triples e=3s+u with head/slot u in {0,i0(s),i1(s)}.
//  S = Q K^T (32x96), P = W .* S with W(t,e)=[s(e)<=t]*rw(t,slot(e)),
//  o_local = P V (32x64), dM[m] = K^T diag(slot==m) V (9x 64x64).
// dM phase balanced: 36 (mi,nt) units striped over 8 waves ({5,5,5,5,4,4,4,4}
// instead of wave0 doing 2 full slots = 8 units).
__global__ __launch_bounds__(512) void mfma_chunk_kernel(
    const float* __restrict__ Y, const float4* __restrict__ gate,
    unsigned short* __restrict__ DMu, float* __restrict__ out)
{
  __shared__ uint32_t Qs[32 * 32];          // bf16 pairs [t][dpair]
  __shared__ uint32_t Ks[96 * 32];          // bf16 pairs [e][dpair]
  __shared__ unsigned short Kts[64 * 104];  // K^T [d][e], pad 96->104
  __shared__ unsigned short Vts[64 * 104];  // V^T [d][e]
  __shared__ unsigned short Ps[32 * 104];   // P   [t][e]
  __shared__ float4 gl[32];
  __shared__ uint32_t su[96];               // slot of triple e

  const int blk = blockIdx.x;
  const int c   = blk & 7;
  const int b   = blk >> 3;
  const int tid = threadIdx.x;
  const int lane = tid & 63;
  const int wv  = tid >> 6;                 // 0..7
  const int quad = lane >> 4;
  const int cl  = lane & 15;
  const int t0  = c * CHL;

  // ---- stage gates + slot ids ----
  if (tid < 32) {
    float4 g = gate[(t0 + tid) * BATCH + b];
    gl[tid] = g;
    su[3 * tid]     = 0u;
    su[3 * tid + 1] = (uint32_t)__float_as_int(g.x);
    su[3 * tid + 2] = (uint32_t)__float_as_int(g.y);
  }
  __syncthreads();

  // ---- stage K (natural + transposed), V (transposed) — float4 gathers ----
  for (int idx = tid; idx < 1536; idx += 512) {      // e = idx>>4, d4 = idx&15
    const int e = idx >> 4, d4 = idx & 15;
    const int s = (e * 171) >> 9;                    // e/3 (exact for e<96)
    const int u = e - 3 * s;
    const int head = (u == 0) ? 0 : (int)su[3 * s + u];
    const float* Yr = Y + ((int64_t)(t0 + s) * BATCH + b) * NPAD;
    float4 kf = *(const float4*)(Yr + head * 64 + 4 * d4);
    unsigned short k0 = (unsigned short)f2bf(kf.x), k1 = (unsigned short)f2bf(kf.y);
    unsigned short k2 = (unsigned short)f2bf(kf.z), k3 = (unsigned short)f2bf(kf.w);
    uint2 kp; kp.x = (uint32_t)k0 | ((uint32_t)k1 << 16);
    kp.y = (uint32_t)k2 | ((uint32_t)k3 << 16);
    *(uint2*)&Ks[e * 32 + 2 * d4] = kp;
    Kts[(4 * d4)     * 104 + e] = k0;
    Kts[(4 * d4 + 1) * 104 + e] = k1;
    Kts[(4 * d4 + 2) * 104 + e] = k2;
    Kts[(4 * d4 + 3) * 104 + e] = k3;
    float4 vf = *(const float4*)(Yr + 576 + head * 64 + 4 * d4);
    Vts[(4 * d4)     * 104 + e] = (unsigned short)f2bf(vf.x);
    Vts[(4 * d4 + 1) * 104 + e] = (unsigned short)f2bf(vf.y);
    Vts[(4 * d4 + 2) * 104 + e] = (unsigned short)f2bf(vf.z);
    Vts[(4 * d4 + 3) * 104 + e] = (unsigned short)f2bf(vf.w);
  }
  {                                                   // Q: 512 entries, one per thread
    const int s = tid >> 4, d4 = tid & 15;
    const float* Yr = Y + ((int64_t)(t0 + s) * BATCH + b) * NPAD;
    float4 qf = *(const float4*)(Yr + 1152 + 4 * d4);
    uint2 qp;
    qp.x = (uint32_t)(unsigned short)f2bf(qf.x) | (((uint32_t)(unsigned short)f2bf(qf.y)) << 16);
    qp.y = (uint32_t)(unsigned short)f2bf(qf.z) | (((uint32_t)(unsigned short)f2bf(qf.w)) << 16);
    *(uint2*)&Qs[s * 32 + 2 * d4] = qp;
  }
  __syncthreads();

  const unsigned short* Qu = (const unsigned short*)Qs;
  const unsigned short* Ku = (const unsigned short*)Ks;

  // ---- phase S + weight + pack P : 12 C-tiles over 8 waves ----
  for (int tileId = wv; tileId < 12; tileId += 8) {
    const int mt = tileId / 6, nt = tileId % 6;
    floatx4 acc = (floatx4){0.f, 0.f, 0.f, 0.f};
#pragma unroll
    for (int kc = 0; kc < 2; kc++) {
      short8 af = *(const short8*)(Qu + (mt * 16 + cl) * 64 + kc * 32 + quad * 8);
      short8 bf = *(const short8*)(Ku + (nt * 16 + cl) * 64 + kc * 32 + quad * 8);
      acc = __builtin_amdgcn_mfma_f32_16x16x32_bf16(af, bf, acc, 0, 0, 0);
    }
    const int e = nt * 16 + cl;
    const int s_e = (e * 171) >> 9;
    const int slot_e = (int)su[e];
#pragma unroll
    for (int r = 0; r < 4; r++) {
      const int t = mt * 16 + quad * 4 + r;
      float4 g = gl[t];
      const int i0t = __float_as_int(g.x), i1t = __float_as_int(g.y);
      float w = (slot_e == 0 ? 1.f : 0.f)
              + (slot_e == i0t ? g.z : 0.f)
              + (slot_e == i1t ? g.w : 0.f);
      w = (s_e <= t) ? w : 0.f;
      Ps[t * 104 + e] = (unsigned short)f2bf(w * acc[r]);
    }
  }
  __syncthreads();

  // ---- phase PV : o_local = P V, 8 C-tiles, one per wave ----
  {
    const int tileId = wv;                    // 0..7
    const int mt = tileId >> 2, nt = tileId & 3;
    floatx4 acc = (floatx4){0.f, 0.f, 0.f, 0.f};
#pragma unroll
    for (int kc = 0; kc < 3; kc++) {
      short8 af = *(const short8*)(Ps  + (mt * 16 + cl) * 104 + kc * 32 + quad * 8);
      short8 bf = *(const short8*)(Vts + (nt * 16 + cl) * 104 + kc * 32 + quad * 8);
      acc = __builtin_amdgcn_mfma_f32_16x16x32_bf16(af, bf, acc, 0, 0, 0);
    }
#pragma unroll
    for (int r = 0; r < 4; r++) {
      const int t = mt * 16 + quad * 4 + r, j = nt * 16 + cl;
      out[(int64_t)(t0 + t) * (BATCH * HID) + b * HID + j] = acc[r];
    }
  }

  // ---- phase dM : per slot m, D = K^T diag(slot==m) V ----
  uint32_t sreg[3][8];
#pragma unroll
  for (int kc = 0; kc < 3; kc++)
#pragma unroll
    for (int jj = 0; jj < 8; jj++)
      sreg[kc][jj] = su[kc * 32 + quad * 8 + jj];

  short8 afc[4][3];
#pragma unroll
  for (int mt = 0; mt < 4; mt++)
#pragma unroll
    for (int kc = 0; kc < 3; kc++)
      afc[mt][kc] = *(const short8*)(Kts + (mt * 16 + cl) * 104 + kc * 32 + quad * 8);

  unsigned short* dmb = DMu + ((int64_t)(c * 32 + b)) * 36864;
  union U8 { short8 s; uint32_t u[4]; };

  for (int uu = wv; uu < 36; uu += 8) {       // (mi,nt) units striped: {5,5,5,5,4,4,4,4}
    const int mi = uu >> 2, nt = uu & 3;
    uint32_t md[3][4];
#pragma unroll
    for (int kc = 0; kc < 3; kc++)
#pragma unroll
      for (int p = 0; p < 4; p++)
        md[kc][p] = ((sreg[kc][2 * p]     == (uint32_t)mi) ? 0x0000ffffu : 0u) |
                    ((sreg[kc][2 * p + 1] == (uint32_t)mi) ? 0xffff0000u : 0u);
    short8 bm[3];
#pragma unroll
    for (int kc = 0; kc < 3; kc++) {
      U8 vv; vv.s = *(const short8*)(Vts + (nt * 16 + cl) * 104 + kc * 32 + quad * 8);
      vv.u[0] &= md[kc][0]; vv.u[1] &= md[kc][1];
      vv.u[2] &= md[kc][2]; vv.u[3] &= md[kc][3];
      bm[kc] = vv.s;
    }
#pragma unroll
    for (int mt = 0; mt < 4; mt++) {
      floatx4 acc = (floatx4){0.f, 0.f, 0.f, 0.f};
#pragma unroll
      for (int kc = 0; kc < 3; kc++)
        acc = __builtin_amdgcn_mfma_f32_16x16x32_bf16(afc[mt][kc], bm[kc], acc, 0, 0, 0);
#pragma unroll
      for (int r = 0; r < 4; r++) {
        const int i = mt * 16 + quad * 4 + r, j = nt * 16 + cl;
        dmb[mi * 4096 + i * 64 + j] = (unsigned short)f2bf(acc[r]);
      }
    }
  }
}

// ---------------- prefix: ΔM(bf16) -> Mstart(bf16) exclusive +M0; writes M_final fp32 ----------------
// NC hardcoded -> all 8 loads issue up front (1 latency instead of 8 dependent round trips).
__global__ void prefix_kernel(const float* __restrict__ M0, uint32_t* __restrict__ DMh,
                              float* __restrict__ out)
{
  int64_t e = (int64_t)blockIdx.x * blockDim.x + threadIdx.x;   // < 32*18432 u32 units
  int b = (int)(e / DM_CB_U32);
  int r = (int)(e % DM_CB_U32);             // m*2048 + i*32 + jpair
  int m = r >> 11, rem = r & 2047, i = rem >> 5, jp = rem & 31;
  int64_t f32i = (int64_t)b * 36864 + m * 4096 + i * 64 + jp * 2;
  float run0 = M0[f32i], run1 = M0[f32i + 1];
  uint32_t u[NC];
#pragma unroll
  for (int cc = 0; cc < NC; cc++)
    u[cc] = DMh[((int64_t)(cc * 32 + b)) * DM_CB_U32 + r];
#pragma unroll
  for (int cc = 0; cc < NC; cc++) {
    int64_t idx = ((int64_t)(cc * 32 + b)) * DM_CB_U32 + r;
    DMh[idx] = ((uint32_t)(unsigned short)f2bf(run0)) |
               (((uint32_t)(unsigned short)f2bf(run1)) << 16);
    run0 += bflo(u[cc]); run1 += bfhi(u[cc]);
  }
  *(float2*)(out + (int64_t)SEQ * BATCH * HID + f32i) = make_float2(run0, run1);
}

// ---------------- corr: o += q·(Mstart[0] + g0·Mstart[i0] + g1·Mstart[i1]) ----------------
// block = (b,c,jh). Mstart staged TRANSPOSED [m][j_local][i] (row stride 68 u16,
// bank stride 34 == 2 mod 32 -> conflict-free b64 reads). Inner loop reads 3x b64
// per 4 i's instead of 6 scalar u16 per 2 i's: ~4x fewer LDS instructions.
__global__ __launch_bounds__(256) void corr_kernel(
    const float* __restrict__ Y, const float4* __restrict__ gate,
    const uint32_t* __restrict__ DMh, float* __restrict__ out)
{
  __shared__ unsigned short MsbT[9 * 32 * 68];   // 39,168 B
  __shared__ float2 qb[32 * 32];                 // q fp32 pairs [t][i/2]
  __shared__ float4 gl[32];
  const int blk = blockIdx.x;
  const int c   = blk & 7;
  const int jh  = (blk >> 3) & 1;
  const int b   = blk >> 4;
  const int tid = threadIdx.x;
  const int t0  = c * CHL;

  if (tid < 32) gl[tid] = gate[(t0 + tid) * BATCH + b];
#pragma unroll
  for (int k = 0; k < 4; k++) {
    int f = tid + 256 * k;                // < 1024
    int t = f >> 5, p = f & 31;
    qb[t * 32 + p] = *(const float2*)(Y + ((int64_t)(t0 + t) * BATCH + b) * NPAD + 1152 + 2 * p);
  }
  const uint32_t* dmb = DMh + ((int64_t)(c * 32 + b)) * DM_CB_U32;
#pragma unroll
  for (int k = 0; k < 36; k++) {
    int f = tid + 256 * k;                // < 9216 u32
    int m = f >> 10, rem = f & 1023, i = rem >> 4, p = rem & 15;
    uint32_t u = dmb[m * 2048 + i * 32 + jh * 16 + p];
    MsbT[(m * 32 + 2 * p)     * 68 + i] = (unsigned short)(u & 0xffffu);
    MsbT[(m * 32 + 2 * p + 1) * 68 + i] = (unsigned short)(u >> 16);
  }
  __syncthreads();

  const int jj = tid & 31;
  const int tg = tid >> 5;
#pragma unroll
  for (int tt = 0; tt < 4; tt++) {
    const int t = tt * 8 + tg;
    float4 g = gl[t];
    const int i0 = __float_as_int(g.x), i1 = __float_as_int(g.y);
    const float g0 = g.z, g1 = g.w;
    const unsigned short* P0 = MsbT + (0  * 32 + jj) * 68;
    const unsigned short* Pa = MsbT + (i0 * 32 + jj) * 68;
    const unsigned short* Pb = MsbT + (i1 * 32 + jj) * 68;
    float acc = 0.f;
#pragma unroll 4
    for (int i4 = 0; i4 < 16; i4++) {     // 4 i's per step
      float2 qq0 = qb[t * 32 + 2 * i4];
      float2 qq1 = qb[t * 32 + 2 * i4 + 1];
      uint2 a0 = *(const uint2*)(P0 + 4 * i4);
      uint2 aa = *(const uint2*)(Pa + 4 * i4);
      uint2 ab = *(const uint2*)(Pb + 4 * i4);
      acc += qq0.x * (bflo(a0.x) + g0 * bflo(aa.x) + g1 * bflo(ab.x));
      acc += qq0.y * (bfhi(a0.x) + g0 * bfhi(aa.x) + g1 * bfhi(ab.x));
      acc += qq1.x * (bflo(a0.y) + g0 * bflo(aa.y) + g1 * bflo(ab.y));
      acc += qq1.y * (bfhi(a0.y) + g0 * bfhi(aa.y) + g1 * bfhi(ab.y));
    }
    float* op = out + (int64_t)(t0 + t) * (BATCH * HID) + b * HID + jh * 32 + jj;
    *op += acc;
  }
}

// ---------------- launch ----------------
extern "C" void kernel_launch(void* const* d_in, const int* in_sizes, int n_in,
                              void* d_out, int out_size, void* d_ws, size_t ws_size,
                              hipStream_t stream)
{
  const float* X  = (const float*)d_in[0];
  const float* M0 = (const float*)d_in[1];
  const float* Wk = (const float*)d_in[2];
  const float* bk = (const float*)d_in[3];
  const float* Wv = (const float*)d_in[4];
  const float* bv = (const float*)d_in[5];
  const float* Wg = (const float*)d_in[6];
  const float* bg = (const float*)d_in[7];
  const float* Wq = (const float*)d_in[8];
  const float* bq = (const float*)d_in[9];

  char* ws = (char*)d_ws;
  short*          Xbf  = (short*)(ws + XBF_OFF);
  short*          Wbf  = (short*)(ws + WBF_OFF);
  float*          bb   = (float*)(ws + BB_OFF);
  float4*         gate = (float4*)(ws + GATE_OFF);
  float*          Y    = (float*)(ws + Y_OFF);
  uint32_t*       DMh  = (uint32_t*)(ws + DMH_OFF);        // overlays Xbf/Wbf (dead after gemm)
  unsigned short* DMu  = (unsigned short*)(ws + DMH_OFF);
  float*          out  = (float*)d_out;

  prep_gate_kernel<<<2304, 256, 0, stream>>>(X, Wk, bk, Wv, bv, Wg, bg, Wq, bq,
                                             Xbf, Wbf, bb, gate);
  dim3 gg(NPAD / 128, ROWS / 128);
  gemm_kernel<<<gg, 256, 0, stream>>>(Xbf, Wbf, bb, Y);
  mfma_chunk_kernel<<<32 * NC, 512, 0, stream>>>(Y, gate, DMu, out);
  prefix_kernel<<<(32 * DM_CB_U32) / 256, 256, 0, stream>>>(M0, DMh, out);
  corr_kernel<<<32 * NC * 2, 256, 0, stream>>>(Y, gate, DMh, out);
}